// Round 6
// baseline (243.688 us; speedup 1.0000x reference)
//
#include <hip/hip_runtime.h>
#include <hip/hip_bf16.h>

// Problem: B=2, S=2048, D_MODEL=1024, H=16, DK=64.
// out = ((l2norm(Q Wq^T) l2norm(K Wk^T)^T)^2 (V Wv^T)) Wo^T   (per head)
// fp32 in/out; internally bf16 MFMA with fp32 accumulation.
//
// Round 6 changes vs round 5 (attn only; R5 counters: MfmaUtil 19%, VALU 37%,
// FETCH 69.7 MB vs 24 ideal, 1M LDS conflicts):
//  - grid axes swapped to (x=bh, y=qt): block%8 == bh%8 pins all consumers of
//    one head's k/v to one XCD -> 4 heads x 512 KB = 2 MB resident in L2,
//    kills the 3x HBM over-fetch + HBM-latency tile fills.
//  - 32 q-rows/wave (128/block, 512 blocks): k/v LDS frag reads (16 KB/iter,
//    identical across waves) amortized over 2x the MFMA.
//  - S^T trick: compute S^T = K.Q^T (swap MFMA operands, free). C-layout then
//    gives each lane 4 consecutive j for fixed q -> P-relayout becomes 8
//    packed ds_write_b64 with __float22bfloat162_rn pair converts (was 16
//    scalar b16 writes + 16 scalar f2bf chains).

#define D_MODEL 1024
#define N_HEADS 16
#define D_K     64
#define BATCH   2
#define SEQ     2048
#define M_TOT   (BATCH * SEQ)   // 4096

typedef short  s16x8 __attribute__((ext_vector_type(8)));   // 8 bf16 = 4 VGPR
typedef float  f32x4 __attribute__((ext_vector_type(4)));   // MFMA C/D frag
typedef unsigned short ushort_t;
typedef ushort_t us4 __attribute__((ext_vector_type(4)));

__device__ __forceinline__ ushort_t f2bf(float f) {
    union { float f; unsigned int u; } x; x.f = f;
    unsigned int u = x.u;
    return (ushort_t)((u + 0x7fffu + ((u >> 16) & 1u)) >> 16);  // RNE
}
__device__ __forceinline__ float bf2f(ushort_t h) {
    union { unsigned int u; float f; } x; x.u = ((unsigned int)h) << 16;
    return x.f;
}
// pack two fp32 -> u32 of two bf16 (RNE), via HIP's packed convert
__device__ __forceinline__ unsigned int pack2bf(float a, float b) {
    union { __hip_bfloat162 h; unsigned int u; } x;
    x.h = __float22bfloat162_rn(float2{a, b});
    return x.u;
}

// async global->LDS, 16B per lane (lane i's lds ptr == wave base + i*16).
__device__ __forceinline__ void gload_lds16(const ushort_t* g, ushort_t* l) {
    __builtin_amdgcn_global_load_lds(
        (__attribute__((address_space(1))) void*)(ushort_t*)g,
        (__attribute__((address_space(3))) void*)l, 16, 0, 0);
}

#define WAIT_VM(n)  asm volatile("s_waitcnt vmcnt(" #n ")" ::: "memory")
#define WAIT_LGKM0  asm volatile("s_waitcnt lgkmcnt(0)" ::: "memory")
#define BARRIER     asm volatile("s_barrier" ::: "memory")

// ---------------------------------------------------------------------------
// fp32 -> bf16 conversion, all 11 inputs in one launch (blockIdx.y = tensor).
// ---------------------------------------------------------------------------
struct ConvArgs {
    const float* src[11];
    ushort_t*    dst[11];
    int          n[11];
};

__global__ __launch_bounds__(256) void convert_kernel(ConvArgs a) {
    const int t = blockIdx.y;
    const int i = (blockIdx.x * 256 + threadIdx.x) * 4;
    if (i >= a.n[t]) return;
    const float4 v = *(const float4*)(a.src[t] + i);
    us4 p;
    p[0] = f2bf(v.x); p[1] = f2bf(v.y); p[2] = f2bf(v.z); p[3] = f2bf(v.w);
    *(us4*)(a.dst[t] + i) = p;
}

// ---------------------------------------------------------------------------
// GEMM body: C[m][n] = sum_k A[m][k]*W[n][k] + bias[n]. BM x 128 tile,
// 4 waves 2x2. 2-deep DMA pipeline, BK=64.
// Per-wave DMAs per tile: MF (A) + 4 (B).  BM=128 -> 8, BM=64 -> 6.
// MODE 0: fp32 row-major store   MODE 1: L2-norm -> (B,H,S,DK) bf16
// MODE 2: transpose -> (B,H,DK,S) bf16
// ---------------------------------------------------------------------------
template <int BM, int MODE>
__device__ __forceinline__ void gemm_body(
    ushort_t* __restrict__ smem,
    const ushort_t* __restrict__ A,
    const ushort_t* __restrict__ W,
    const ushort_t* __restrict__ bias,
    ushort_t* __restrict__ out,
    float* __restrict__ outf,
    int bx, int by)
{
    static_assert(BM == 64 || BM == 128, "");
    constexpr int K    = 1024;
    constexpr int MF   = BM / 32;
    constexpr int BUFW = (BM + 128) * 64;   // words per LDS buffer
    constexpr int NIT  = K / 64;            // 16

    const int t    = threadIdx.x;
    const int wave = t >> 6;
    const int lane = t & 63;
    const int quad = lane >> 4;
    const int lc   = lane & 15;
    const int wm   = wave >> 1;
    const int wn   = wave & 1;
    const int m0   = bx * BM;
    const int n0   = by * 128;

    f32x4 acc[MF][4];
    const f32x4 zero = {0.f, 0.f, 0.f, 0.f};
#pragma unroll
    for (int i = 0; i < MF; ++i)
#pragma unroll
        for (int j = 0; j < 4; ++j) acc[i][j] = zero;

    auto stage = [&](int buf, int k0) {
        ushort_t* Ast = smem + buf * BUFW;
        ushort_t* Bst = Ast + BM * 64;
#pragma unroll
        for (int c = 0; c < MF; ++c) {
            int idx = c * 256 + t;
            int row = idx >> 3, phys = idx & 7;
            int col = (phys ^ (row & 7)) * 8;
            gload_lds16(A + (size_t)(m0 + row) * K + k0 + col, Ast + idx * 8);
        }
#pragma unroll
        for (int c = 0; c < 4; ++c) {
            int idx = c * 256 + t;
            int row = idx >> 3, phys = idx & 7;
            int col = (phys ^ (row & 7)) * 8;
            gload_lds16(W + (size_t)(n0 + row) * K + k0 + col, Bst + idx * 8);
        }
    };
    auto comp = [&](int buf) {
        ushort_t* Ast = smem + buf * BUFW;
        ushort_t* Bst = Ast + BM * 64;
#pragma unroll
        for (int ks = 0; ks < 2; ++ks) {
            const int ph = ((ks * 4 + quad) ^ (lc & 7)) * 8;
            s16x8 a[MF], b[4];
#pragma unroll
            for (int i = 0; i < MF; ++i)
                a[i] = *(const s16x8*)(Ast + (wm * (BM / 2) + i * 16 + lc) * 64 + ph);
#pragma unroll
            for (int i = 0; i < 4; ++i)
                b[i] = *(const s16x8*)(Bst + (wn * 64 + i * 16 + lc) * 64 + ph);
#pragma unroll
            for (int mf = 0; mf < MF; ++mf)
#pragma unroll
                for (int nf = 0; nf < 4; ++nf)
                    acc[mf][nf] = __builtin_amdgcn_mfma_f32_16x16x32_bf16(
                        a[mf], b[nf], acc[mf][nf], 0, 0, 0);
        }
    };

    stage(0, 0);
    stage(1, 64);
    for (int it = 0; it < NIT - 2; ++it) {
        if constexpr (BM == 128) WAIT_VM(8); else WAIT_VM(6);
        BARRIER;                  // tile `it` fully landed (all waves waited)
        comp(it & 1);
        WAIT_LGKM0;               // my frag reads are in registers
        BARRIER;                  // all waves done reading buf(it&1)
        stage(it & 1, (it + 2) * 64);
    }
    if constexpr (BM == 128) WAIT_VM(8); else WAIT_VM(6);
    BARRIER;
    comp((NIT - 2) & 1);
    WAIT_VM(0);
    BARRIER;
    comp((NIT - 1) & 1);

    float bv[4];
#pragma unroll
    for (int nf = 0; nf < 4; ++nf) bv[nf] = bf2f(bias[n0 + wn * 64 + nf * 16 + lc]);

    if (MODE == 0) {
#pragma unroll
        for (int mf = 0; mf < MF; ++mf)
#pragma unroll
            for (int nf = 0; nf < 4; ++nf)
#pragma unroll
                for (int r = 0; r < 4; ++r) {
                    int mg = m0 + wm * (BM / 2) + mf * 16 + quad * 4 + r;
                    int ng = n0 + wn * 64 + nf * 16 + lc;
                    outf[(size_t)mg * D_MODEL + ng] = acc[mf][nf][r] + bv[nf];
                }
    } else if (MODE == 1) {
        // wave's 64 cols == one head; row-of-64 lives in 16 lanes x 4 nf regs
#pragma unroll
        for (int mf = 0; mf < MF; ++mf)
#pragma unroll
            for (int r = 0; r < 4; ++r) {
                float ss = 0.f;
#pragma unroll
                for (int nf = 0; nf < 4; ++nf) {
                    float v = acc[mf][nf][r] + bv[nf];
                    acc[mf][nf][r] = v;
                    ss += v * v;
                }
                ss += __shfl_xor(ss, 1);
                ss += __shfl_xor(ss, 2);
                ss += __shfl_xor(ss, 4);
                ss += __shfl_xor(ss, 8);
                float inv = rsqrtf(ss + 1e-8f);
                int mg = m0 + wm * (BM / 2) + mf * 16 + quad * 4 + r;
                int b  = mg >> 11;
                int s  = mg & 2047;
#pragma unroll
                for (int nf = 0; nf < 4; ++nf) {
                    int ng = n0 + wn * 64 + nf * 16 + lc;
                    int h = ng >> 6, d = ng & 63;
                    out[(((size_t)(b * N_HEADS + h)) * SEQ + s) * D_K + d] =
                        f2bf(acc[mf][nf][r] * inv);
                }
            }
    } else {
        // MODE 2: transpose wave's 64(s)x64(d) tile through per-wave LDS
        // region [64 d][stride 72]. Block barrier first: other waves may
        // still be reading buf1 which these regions overlap.
        __syncthreads();
        ushort_t* vt = smem + wave * (64 * 72);
#pragma unroll
        for (int mf = 0; mf < 4; ++mf)
#pragma unroll
            for (int nf = 0; nf < 4; ++nf) {
                us4 p;
#pragma unroll
                for (int r = 0; r < 4; ++r) p[r] = f2bf(acc[mf][nf][r] + bv[nf]);
                *(us4*)(vt + (nf * 16 + lc) * 72 + mf * 16 + quad * 4) = p;
            }
        WAIT_LGKM0;   // wave-private region: wave-local fence suffices
#pragma unroll
        for (int r = 0; r < 8; ++r) {
            int d  = r * 8 + (lane >> 3);
            int so = (lane & 7) * 8;
            uint4 val = *(const uint4*)(vt + d * 72 + so);
            int mg = m0 + wm * 64 + so;
            int b  = mg >> 11;
            int s  = mg & 2047;
            int ng = n0 + wn * 64 + d;
            int h = ng >> 6, dh = ng & 63;
            *(uint4*)(out + (((size_t)(b * N_HEADS + h)) * D_K + dh) * SEQ + s) = val;
        }
    }
}

// fused Q/K/V projections: grid.z selects tensor (768 blocks)
__global__ __launch_bounds__(256) void qkv_kernel(
    const ushort_t* __restrict__ Qb, const ushort_t* __restrict__ Kb,
    const ushort_t* __restrict__ Vb,
    const ushort_t* __restrict__ Wq, const ushort_t* __restrict__ Wk,
    const ushort_t* __restrict__ Wv,
    const ushort_t* __restrict__ bq, const ushort_t* __restrict__ bk,
    const ushort_t* __restrict__ bv,
    ushort_t* __restrict__ qn, ushort_t* __restrict__ kn,
    ushort_t* __restrict__ vT)
{
    __shared__ __align__(16) ushort_t smem[2 * (128 + 128) * 64];  // 64 KB
    const int z = blockIdx.z;
    if (z == 0)
        gemm_body<128, 1>(smem, Qb, Wq, bq, qn, nullptr, blockIdx.x, blockIdx.y);
    else if (z == 1)
        gemm_body<128, 1>(smem, Kb, Wk, bk, kn, nullptr, blockIdx.x, blockIdx.y);
    else
        gemm_body<128, 2>(smem, Vb, Wv, bv, vT, nullptr, blockIdx.x, blockIdx.y);
}

// output projection: BM=64 -> 512 blocks
__global__ __launch_bounds__(256) void wo_kernel(
    const ushort_t* __restrict__ A, const ushort_t* __restrict__ W,
    const ushort_t* __restrict__ bias, float* __restrict__ outf)
{
    __shared__ __align__(16) ushort_t smem[2 * (64 + 128) * 64];   // 48 KB
    gemm_body<64, 0>(smem, A, W, bias, nullptr, outf, blockIdx.x, blockIdx.y);
}

// ---------------------------------------------------------------------------
// Attention: per (b,h): out = (qn kn^T)^2 v.
// Grid (x=bh 32, y=qt 16) -> 512 blocks, bh%8 pins a head to one XCD's L2.
// 4 waves x 32 q-rows = 128-q block. 2-deep DMA pipeline on 64-wide k-tiles.
// S^T = K.Q^T: lane holds fixed q, 4 consecutive j -> packed b64 P writes.
// ---------------------------------------------------------------------------
__global__ __launch_bounds__(256) void attn_kernel(
    const ushort_t* __restrict__ qn,
    const ushort_t* __restrict__ kn,
    const ushort_t* __restrict__ vT,
    ushort_t* __restrict__ attn_out)
{
    // buf i: kst = smem + i*8192 [64 j][64 d], vst = +4096 [64 d][64 j]
    // pl: per-wave [32 q][stride 72]
    __shared__ __align__(16) ushort_t smem[2 * 8192 + 4 * 32 * 72];  // 50.4 KB

    const int t    = threadIdx.x;
    const int wave = t >> 6;
    const int lane = t & 63;
    const int quad = lane >> 4;
    const int lc   = lane & 15;
    const int bh   = blockIdx.x;       // 0..31  (block%8 == bh%8 -> XCD pin)
    const int qt   = blockIdx.y;       // 0..15
    const int b    = bh >> 4;
    const int h    = bh & 15;

    const ushort_t* qb = qn + (size_t)bh * SEQ * D_K;
    const ushort_t* kb = kn + (size_t)bh * SEQ * D_K;
    const ushort_t* vb = vT + (size_t)bh * D_K * SEQ;
    const int q0 = qt * 128 + wave * 32;

    // q B-frags (S^T: Q is the B operand), reused across all 32 k-tiles
    s16x8 aq[2][2];
#pragma unroll
    for (int mf = 0; mf < 2; ++mf)
#pragma unroll
        for (int ks = 0; ks < 2; ++ks)
            aq[mf][ks] = *(const s16x8*)(qb + (size_t)(q0 + mf * 16 + lc) * D_K +
                                         ks * 32 + quad * 8);

    f32x4 oacc[2][4];
    const f32x4 zero = {0.f, 0.f, 0.f, 0.f};
#pragma unroll
    for (int mf = 0; mf < 2; ++mf)
#pragma unroll
        for (int df = 0; df < 4; ++df) oacc[mf][df] = zero;

    ushort_t* pl = smem + 2 * 8192 + wave * 32 * 72;  // per-wave [32 q][72]

    auto stage = [&](int buf, int j0) {
        ushort_t* kst = smem + buf * 8192;
        ushort_t* vst = kst + 4096;
#pragma unroll
        for (int c = 0; c < 2; ++c) {
            int idx = c * 256 + t;
            int row = idx >> 3, phys = idx & 7;
            int col = (phys ^ (row & 7)) * 8;
            gload_lds16(kb + (size_t)(j0 + row) * D_K + col, kst + idx * 8);
            gload_lds16(vb + (size_t)row * SEQ + j0 + col, vst + idx * 8);
        }
    };
    auto comp = [&](int buf) {
        ushort_t* kst = smem + buf * 8192;
        ushort_t* vst = kst + 4096;
        const int ph0 = ((0 * 4 + quad) ^ (lc & 7)) * 8;
        const int ph1 = ((1 * 4 + quad) ^ (lc & 7)) * 8;
        // k A-frags (rows j)
        s16x8 bk[4][2];
#pragma unroll
        for (int jf = 0; jf < 4; ++jf) {
            bk[jf][0] = *(const s16x8*)(kst + (jf * 16 + lc) * 64 + ph0);
            bk[jf][1] = *(const s16x8*)(kst + (jf * 16 + lc) * 64 + ph1);
        }
        // S^T[j][q]: A = K rows, B = Q rows. Lane: q = lc (fixed),
        // j = jf*16 + quad*4 + r (4 consecutive).
        f32x4 s[4][2];
#pragma unroll
        for (int jf = 0; jf < 4; ++jf)
#pragma unroll
            for (int mf = 0; mf < 2; ++mf) {
                s[jf][mf] = zero;
#pragma unroll
                for (int ks = 0; ks < 2; ++ks)
                    s[jf][mf] = __builtin_amdgcn_mfma_f32_16x16x32_bf16(
                        bk[jf][ks], aq[mf][ks], s[jf][mf], 0, 0, 0);
            }
        // square -> packed bf16 pairs -> one b64 write per (jf,mf)
#pragma unroll
        for (int jf = 0; jf < 4; ++jf)
#pragma unroll
            for (int mf = 0; mf < 2; ++mf) {
                float p0 = s[jf][mf][0] * s[jf][mf][0];
                float p1 = s[jf][mf][1] * s[jf][mf][1];
                float p2 = s[jf][mf][2] * s[jf][mf][2];
                float p3 = s[jf][mf][3] * s[jf][mf][3];
                uint2 w = {pack2bf(p0, p1), pack2bf(p2, p3)};
                *(uint2*)(pl + (mf * 16 + lc) * 72 + jf * 16 + quad * 4) = w;
            }
        // v B-frags (rows d of vst)
        s16x8 bvf[4][2];
#pragma unroll
        for (int df = 0; df < 4; ++df) {
            bvf[df][0] = *(const s16x8*)(vst + (df * 16 + lc) * 64 + ph0);
            bvf[df][1] = *(const s16x8*)(vst + (df * 16 + lc) * 64 + ph1);
        }
        WAIT_LGKM0;   // pl writes visible wave-locally
        // P A-frags [q][j]
        s16x8 aa[2][2];
#pragma unroll
        for (int mf = 0; mf < 2; ++mf)
#pragma unroll
            for (int ks = 0; ks < 2; ++ks)
                aa[mf][ks] = *(const s16x8*)(pl + (mf * 16 + lc) * 72 +
                                             ks * 32 + quad * 8);
#pragma unroll
        for (int mf = 0; mf < 2; ++mf)
#pragma unroll
            for (int df = 0; df < 4; ++df)
#pragma unroll
                for (int ks = 0; ks < 2; ++ks)
                    oacc[mf][df] = __builtin_amdgcn_mfma_f32_16x16x32_bf16(
                        aa[mf][ks], bvf[df][ks], oacc[mf][df], 0, 0, 0);
    };

    constexpr int NT = 32;
    stage(0, 0);
    stage(1, 64);
    for (int it = 0; it < NT - 2; ++it) {
        WAIT_VM(4);
        BARRIER;
        comp(it & 1);
        WAIT_LGKM0;
        BARRIER;
        stage(it & 1, (it + 2) * 64);
    }
    WAIT_VM(4);
    BARRIER;
    comp((NT - 2) & 1);
    WAIT_VM(0);
    BARRIER;
    comp((NT - 1) & 1);

    // store to (B,S,D) head-interleaved bf16 for the output projection
#pragma unroll
    for (int mf = 0; mf < 2; ++mf)
#pragma unroll
        for (int df = 0; df < 4; ++df)
#pragma unroll
            for (int r = 0; r < 4; ++r) {
                int s = q0 + mf * 16 + quad * 4 + r;
                int d = df * 16 + lc;
                attn_out[((size_t)(b * SEQ + s)) * D_MODEL + h * D_K + d] =
                    f2bf(oacc[mf][df][r]);
            }
}

extern "C" void kernel_launch(void* const* d_in, const int* in_sizes, int n_in,
                              void* d_out, int out_size, void* d_ws, size_t ws_size,
                              hipStream_t stream)
{
    const float* Qf   = (const float*)d_in[0];
    const float* Kf   = (const float*)d_in[1];
    const float* Vf   = (const float*)d_in[2];
    const float* Wqf  = (const float*)d_in[3];
    const float* Wqbf = (const float*)d_in[4];
    const float* Wkf  = (const float*)d_in[5];
    const float* Wkbf = (const float*)d_in[6];
    const float* Wvf  = (const float*)d_in[7];
    const float* Wvbf = (const float*)d_in[8];
    const float* Wof  = (const float*)d_in[9];
    const float* Wobf = (const float*)d_in[10];

    const size_t NM = (size_t)M_TOT * D_MODEL;
    const size_t NW = (size_t)D_MODEL * D_MODEL;
    const size_t NB = D_MODEL;

    ushort_t* p = (ushort_t*)d_ws;
    ushort_t* Qb  = p;  p += NM;
    ushort_t* Kb  = p;  p += NM;
    ushort_t* Vb  = p;  p += NM;
    ushort_t* Wq  = p;  p += NW;
    ushort_t* Wk  = p;  p += NW;
    ushort_t* Wv  = p;  p += NW;
    ushort_t* Wo  = p;  p += NW;
    ushort_t* bq  = p;  p += NB;
    ushort_t* bk  = p;  p += NB;
    ushort_t* bvv = p;  p += NB;
    ushort_t* bo  = p;  p += NB;
    ushort_t* qn  = p;  p += NM;   // (B,H,S,DK)
    ushort_t* kn  = p;  p += NM;   // (B,H,S,DK)
    ushort_t* vT  = p;  p += NM;   // (B,H,DK,S)
    ushort_t* ao  = p;  p += NM;   // (B,S,D)

    ConvArgs ca;
    ca.src[0] = Qf;   ca.dst[0] = Qb;  ca.n[0] = (int)NM;
    ca.src[1] = Kf;   ca.dst[1] = Kb;  ca.n[1] = (int)NM;
    ca.src[2] = Vf;   ca.dst[2] = Vb;  ca.n[2] = (int)NM;
    ca.src[3] = Wqf;  ca.dst[3] = Wq;  ca.n[3] = (int)NW;
    ca.src[4] = Wkf;  ca.dst[4] = Wk;  ca.n[4] = (int)NW;
    ca.src[5] = Wvf;  ca.dst[5] = Wv;  ca.n[5] = (int)NW;
    ca.src[6] = Wof;  ca.dst[6] = Wo;  ca.n[6] = (int)NW;
    ca.src[7] = Wqbf; ca.dst[7] = bq;  ca.n[7] = (int)NB;
    ca.src[8] = Wkbf; ca.dst[8] = bk;  ca.n[8] = (int)NB;
    ca.src[9] = Wvbf; ca.dst[9] = bvv; ca.n[9] = (int)NB;
    ca.src[10] = Wobf; ca.dst[10] = bo; ca.n[10] = (int)NB;

    dim3 blk(256);
    convert_kernel<<<dim3((unsigned)(NM / (256 * 4)), 11), blk, 0, stream>>>(ca);

    qkv_kernel<<<dim3(M_TOT / 128, D_MODEL / 128, 3), blk, 0, stream>>>(
        Qb, Kb, Vb, Wq, Wk, Wv, bq, bk, bvv, qn, kn, vT);
    attn_kernel<<<dim3(BATCH * N_HEADS, SEQ / 128), blk, 0, stream>>>(qn, kn, vT, ao);
    wo_kernel<<<dim3(M_TOT / 64, D_MODEL / 128), blk, 0, stream>>>(
        ao, Wo, bo, (float*)d_out);
}

// Round 7
// 237.728 us; speedup vs baseline: 1.0251x; 1.0251x over previous
//
#include <hip/hip_runtime.h>
#include <hip/hip_bf16.h>

// Problem: B=2, S=2048, D_MODEL=1024, H=16, DK=64.
// out = ((l2norm(Q Wq^T) l2norm(K Wk^T)^T)^2 (V Wv^T)) Wo^T   (per head)
// fp32 in/out; internally bf16 MFMA with fp32 accumulation.
//
// Round 7 changes vs round 6 (attn only; R6: LDS-BW bound, 20 b128/wave-iter,
// 3.1M conflicts from the P LDS round-trip, MfmaUtil 22%):
//  - waves partition the k-tile over j (16-wide slices) instead of q:
//    * QK^T A-frags: 2 b128/iter (own 16 K-rows); Q lives in registers.
//    * S^T C-layout [j=quad*4+r][q=lc] IS the A-layout of 16x16x16 MFMA
//      -> squared P goes register->register into PV. No pl LDS round-trip,
//      no lgkm serialization, no conflicts.
//    * PV: K=16 MFMA over the wave's j-slice; V^T B-frags: 4 b64/iter.
//    LDS traffic per wave-iter: 20 -> ~4 b128-equivalents.
//  - block-end cross-wave j-reduction of partial O via padded LDS (4 rounds,
//    stride-68 fp32, 2-way banks = free), once per block.
//  - grid stays (x=bh) -> XCD pin (R6-verified: FETCH 69.7->12.3 MB).

#define D_MODEL 1024
#define N_HEADS 16
#define D_K     64
#define BATCH   2
#define SEQ     2048
#define M_TOT   (BATCH * SEQ)   // 4096

typedef short  s16x8 __attribute__((ext_vector_type(8)));   // 8 bf16 = 4 VGPR
typedef short  s16x4 __attribute__((ext_vector_type(4)));   // 4 bf16 = 2 VGPR
typedef float  f32x4 __attribute__((ext_vector_type(4)));   // MFMA C/D frag
typedef unsigned short ushort_t;
typedef ushort_t us4 __attribute__((ext_vector_type(4)));

__device__ __forceinline__ ushort_t f2bf(float f) {
    union { float f; unsigned int u; } x; x.f = f;
    unsigned int u = x.u;
    return (ushort_t)((u + 0x7fffu + ((u >> 16) & 1u)) >> 16);  // RNE
}
__device__ __forceinline__ float bf2f(ushort_t h) {
    union { unsigned int u; float f; } x; x.u = ((unsigned int)h) << 16;
    return x.f;
}
// pack two fp32 -> u32 of two bf16 (RNE)
__device__ __forceinline__ unsigned int pack2bf(float a, float b) {
    union { __hip_bfloat162 h; unsigned int u; } x;
    x.h = __float22bfloat162_rn(float2{a, b});
    return x.u;
}

// K=16 bf16 MFMA (v_mfma_f32_16x16x16_bf16, A/B = 2 VGPRs): builtin if
// available, else raw asm (instruction exists on gfx950 per ISA ref §10).
#if defined(__has_builtin)
#if __has_builtin(__builtin_amdgcn_mfma_f32_16x16x16bf16_1k)
#define MFMA16K16(a, b, c) __builtin_amdgcn_mfma_f32_16x16x16bf16_1k(a, b, c, 0, 0, 0)
#endif
#endif
#ifndef MFMA16K16
__device__ __forceinline__ f32x4 mfma16k16_asm(s16x4 a, s16x4 b, f32x4 c) {
    f32x4 d;
    asm volatile("v_mfma_f32_16x16x16_bf16 %0, %1, %2, %3\n\ts_nop 1"
                 : "=v"(d) : "v"(a), "v"(b), "v"(c));
    return d;
}
#define MFMA16K16(a, b, c) mfma16k16_asm(a, b, c)
#endif

// async global->LDS, 16B per lane (lane i's lds ptr == wave base + i*16).
__device__ __forceinline__ void gload_lds16(const ushort_t* g, ushort_t* l) {
    __builtin_amdgcn_global_load_lds(
        (__attribute__((address_space(1))) void*)(ushort_t*)g,
        (__attribute__((address_space(3))) void*)l, 16, 0, 0);
}

#define WAIT_VM(n)  asm volatile("s_waitcnt vmcnt(" #n ")" ::: "memory")
#define WAIT_LGKM0  asm volatile("s_waitcnt lgkmcnt(0)" ::: "memory")
#define BARRIER     asm volatile("s_barrier" ::: "memory")

// ---------------------------------------------------------------------------
// fp32 -> bf16 conversion, all 11 inputs in one launch (blockIdx.y = tensor).
// ---------------------------------------------------------------------------
struct ConvArgs {
    const float* src[11];
    ushort_t*    dst[11];
    int          n[11];
};

__global__ __launch_bounds__(256) void convert_kernel(ConvArgs a) {
    const int t = blockIdx.y;
    const int i = (blockIdx.x * 256 + threadIdx.x) * 4;
    if (i >= a.n[t]) return;
    const float4 v = *(const float4*)(a.src[t] + i);
    us4 p;
    p[0] = f2bf(v.x); p[1] = f2bf(v.y); p[2] = f2bf(v.z); p[3] = f2bf(v.w);
    *(us4*)(a.dst[t] + i) = p;
}

// ---------------------------------------------------------------------------
// GEMM body (unchanged from R6): BM x 128 tile, 4 waves 2x2, 2-deep DMA
// pipeline, BK=64. MODE 0: fp32 store  MODE 1: L2-norm -> (B,H,S,DK)
// MODE 2: transpose -> (B,H,DK,S)
// ---------------------------------------------------------------------------
template <int BM, int MODE>
__device__ __forceinline__ void gemm_body(
    ushort_t* __restrict__ smem,
    const ushort_t* __restrict__ A,
    const ushort_t* __restrict__ W,
    const ushort_t* __restrict__ bias,
    ushort_t* __restrict__ out,
    float* __restrict__ outf,
    int bx, int by)
{
    static_assert(BM == 64 || BM == 128, "");
    constexpr int K    = 1024;
    constexpr int MF   = BM / 32;
    constexpr int BUFW = (BM + 128) * 64;
    constexpr int NIT  = K / 64;

    const int t    = threadIdx.x;
    const int wave = t >> 6;
    const int lane = t & 63;
    const int quad = lane >> 4;
    const int lc   = lane & 15;
    const int wm   = wave >> 1;
    const int wn   = wave & 1;
    const int m0   = bx * BM;
    const int n0   = by * 128;

    f32x4 acc[MF][4];
    const f32x4 zero = {0.f, 0.f, 0.f, 0.f};
#pragma unroll
    for (int i = 0; i < MF; ++i)
#pragma unroll
        for (int j = 0; j < 4; ++j) acc[i][j] = zero;

    auto stage = [&](int buf, int k0) {
        ushort_t* Ast = smem + buf * BUFW;
        ushort_t* Bst = Ast + BM * 64;
#pragma unroll
        for (int c = 0; c < MF; ++c) {
            int idx = c * 256 + t;
            int row = idx >> 3, phys = idx & 7;
            int col = (phys ^ (row & 7)) * 8;
            gload_lds16(A + (size_t)(m0 + row) * K + k0 + col, Ast + idx * 8);
        }
#pragma unroll
        for (int c = 0; c < 4; ++c) {
            int idx = c * 256 + t;
            int row = idx >> 3, phys = idx & 7;
            int col = (phys ^ (row & 7)) * 8;
            gload_lds16(W + (size_t)(n0 + row) * K + k0 + col, Bst + idx * 8);
        }
    };
    auto comp = [&](int buf) {
        ushort_t* Ast = smem + buf * BUFW;
        ushort_t* Bst = Ast + BM * 64;
#pragma unroll
        for (int ks = 0; ks < 2; ++ks) {
            const int ph = ((ks * 4 + quad) ^ (lc & 7)) * 8;
            s16x8 a[MF], b[4];
#pragma unroll
            for (int i = 0; i < MF; ++i)
                a[i] = *(const s16x8*)(Ast + (wm * (BM / 2) + i * 16 + lc) * 64 + ph);
#pragma unroll
            for (int i = 0; i < 4; ++i)
                b[i] = *(const s16x8*)(Bst + (wn * 64 + i * 16 + lc) * 64 + ph);
#pragma unroll
            for (int mf = 0; mf < MF; ++mf)
#pragma unroll
                for (int nf = 0; nf < 4; ++nf)
                    acc[mf][nf] = __builtin_amdgcn_mfma_f32_16x16x32_bf16(
                        a[mf], b[nf], acc[mf][nf], 0, 0, 0);
        }
    };

    stage(0, 0);
    stage(1, 64);
    for (int it = 0; it < NIT - 2; ++it) {
        if constexpr (BM == 128) WAIT_VM(8); else WAIT_VM(6);
        BARRIER;
        comp(it & 1);
        WAIT_LGKM0;
        BARRIER;
        stage(it & 1, (it + 2) * 64);
    }
    if constexpr (BM == 128) WAIT_VM(8); else WAIT_VM(6);
    BARRIER;
    comp((NIT - 2) & 1);
    WAIT_VM(0);
    BARRIER;
    comp((NIT - 1) & 1);

    float bv[4];
#pragma unroll
    for (int nf = 0; nf < 4; ++nf) bv[nf] = bf2f(bias[n0 + wn * 64 + nf * 16 + lc]);

    if (MODE == 0) {
#pragma unroll
        for (int mf = 0; mf < MF; ++mf)
#pragma unroll
            for (int nf = 0; nf < 4; ++nf)
#pragma unroll
                for (int r = 0; r < 4; ++r) {
                    int mg = m0 + wm * (BM / 2) + mf * 16 + quad * 4 + r;
                    int ng = n0 + wn * 64 + nf * 16 + lc;
                    outf[(size_t)mg * D_MODEL + ng] = acc[mf][nf][r] + bv[nf];
                }
    } else if (MODE == 1) {
#pragma unroll
        for (int mf = 0; mf < MF; ++mf)
#pragma unroll
            for (int r = 0; r < 4; ++r) {
                float ss = 0.f;
#pragma unroll
                for (int nf = 0; nf < 4; ++nf) {
                    float v = acc[mf][nf][r] + bv[nf];
                    acc[mf][nf][r] = v;
                    ss += v * v;
                }
                ss += __shfl_xor(ss, 1);
                ss += __shfl_xor(ss, 2);
                ss += __shfl_xor(ss, 4);
                ss += __shfl_xor(ss, 8);
                float inv = rsqrtf(ss + 1e-8f);
                int mg = m0 + wm * (BM / 2) + mf * 16 + quad * 4 + r;
                int b  = mg >> 11;
                int s  = mg & 2047;
#pragma unroll
                for (int nf = 0; nf < 4; ++nf) {
                    int ng = n0 + wn * 64 + nf * 16 + lc;
                    int h = ng >> 6, d = ng & 63;
                    out[(((size_t)(b * N_HEADS + h)) * SEQ + s) * D_K + d] =
                        f2bf(acc[mf][nf][r] * inv);
                }
            }
    } else {
        __syncthreads();
        ushort_t* vt = smem + wave * (64 * 72);
#pragma unroll
        for (int mf = 0; mf < 4; ++mf)
#pragma unroll
            for (int nf = 0; nf < 4; ++nf) {
                us4 p;
#pragma unroll
                for (int r = 0; r < 4; ++r) p[r] = f2bf(acc[mf][nf][r] + bv[nf]);
                *(us4*)(vt + (nf * 16 + lc) * 72 + mf * 16 + quad * 4) = p;
            }
        WAIT_LGKM0;
#pragma unroll
        for (int r = 0; r < 8; ++r) {
            int d  = r * 8 + (lane >> 3);
            int so = (lane & 7) * 8;
            uint4 val = *(const uint4*)(vt + d * 72 + so);
            int mg = m0 + wm * 64 + so;
            int b  = mg >> 11;
            int s  = mg & 2047;
            int ng = n0 + wn * 64 + d;
            int h = ng >> 6, dh = ng & 63;
            *(uint4*)(out + (((size_t)(b * N_HEADS + h)) * D_K + dh) * SEQ + s) = val;
        }
    }
}

__global__ __launch_bounds__(256) void qkv_kernel(
    const ushort_t* __restrict__ Qb, const ushort_t* __restrict__ Kb,
    const ushort_t* __restrict__ Vb,
    const ushort_t* __restrict__ Wq, const ushort_t* __restrict__ Wk,
    const ushort_t* __restrict__ Wv,
    const ushort_t* __restrict__ bq, const ushort_t* __restrict__ bk,
    const ushort_t* __restrict__ bv,
    ushort_t* __restrict__ qn, ushort_t* __restrict__ kn,
    ushort_t* __restrict__ vT)
{
    __shared__ __align__(16) ushort_t smem[2 * (128 + 128) * 64];  // 64 KB
    const int z = blockIdx.z;
    if (z == 0)
        gemm_body<128, 1>(smem, Qb, Wq, bq, qn, nullptr, blockIdx.x, blockIdx.y);
    else if (z == 1)
        gemm_body<128, 1>(smem, Kb, Wk, bk, kn, nullptr, blockIdx.x, blockIdx.y);
    else
        gemm_body<128, 2>(smem, Vb, Wv, bv, vT, nullptr, blockIdx.x, blockIdx.y);
}

__global__ __launch_bounds__(256) void wo_kernel(
    const ushort_t* __restrict__ A, const ushort_t* __restrict__ W,
    const ushort_t* __restrict__ bias, float* __restrict__ outf)
{
    __shared__ __align__(16) ushort_t smem[2 * (64 + 128) * 64];   // 48 KB
    gemm_body<64, 0>(smem, A, W, bias, nullptr, outf, blockIdx.x, blockIdx.y);
}

// ---------------------------------------------------------------------------
// Attention: per (b,h): out = (qn kn^T)^2 v.
// Grid (x=bh 32, y=qt 32) -> 1024 blocks; bh%8 pins a head to one XCD's L2.
// 64 q-rows/block; each wave owns a 16-wide j-slice of every 64-wide k-tile.
// S^T = K_slice . Q^T (16x16x32); its C-layout == 16x16x16 A-layout, so the
// squared P feeds PV register-to-register. Block-end j-reduction via LDS.
// ---------------------------------------------------------------------------
__global__ __launch_bounds__(256) void attn_kernel(
    const ushort_t* __restrict__ qn,
    const ushort_t* __restrict__ kn,
    const ushort_t* __restrict__ vT,
    ushort_t* __restrict__ attn_out)
{
    // staging: buf i at smem+i*8192 (kst 4096 + vst 4096 ushorts)
    __shared__ __align__(16) ushort_t smem[2 * 8192];     // 32 KB
    __shared__ float red[3 * 16 * 68];                    // 13 KB, stride 68

    const int t    = threadIdx.x;
    const int wave = t >> 6;
    const int lane = t & 63;
    const int quad = lane >> 4;
    const int lc   = lane & 15;
    const int bh   = blockIdx.x;       // 0..31 (bh%8 -> XCD pin)
    const int qt   = blockIdx.y;       // 0..31
    const int b    = bh >> 4;
    const int h    = bh & 15;

    const ushort_t* qb = qn + (size_t)bh * SEQ * D_K;
    const ushort_t* kb = kn + (size_t)bh * SEQ * D_K;
    const ushort_t* vb = vT + (size_t)bh * D_K * SEQ;
    const int q0 = qt * 64;
    const int jw = wave * 16;          // wave's j-slice offset in each k-tile

    // Q B-frags: 4 mf x 2 ks, reused across all 32 k-tiles (no LDS)
    s16x8 qf[4][2];
#pragma unroll
    for (int mf = 0; mf < 4; ++mf)
#pragma unroll
        for (int ks = 0; ks < 2; ++ks)
            qf[mf][ks] = *(const s16x8*)(qb + (size_t)(q0 + mf * 16 + lc) * D_K +
                                         ks * 32 + quad * 8);

    f32x4 oacc[4][4];                  // [mf(q)][df(d)] partial over j-slice
    const f32x4 zero = {0.f, 0.f, 0.f, 0.f};
#pragma unroll
    for (int mf = 0; mf < 4; ++mf)
#pragma unroll
        for (int df = 0; df < 4; ++df) oacc[mf][df] = zero;

    auto stage = [&](int buf, int j0) {
        ushort_t* kst = smem + buf * 8192;
        ushort_t* vst = kst + 4096;
#pragma unroll
        for (int c = 0; c < 2; ++c) {
            int idx = c * 256 + t;
            int row = idx >> 3, phys = idx & 7;
            int col = (phys ^ (row & 7)) * 8;
            gload_lds16(kb + (size_t)(j0 + row) * D_K + col, kst + idx * 8);
            gload_lds16(vb + (size_t)row * SEQ + j0 + col, vst + idx * 8);
        }
    };
    auto comp = [&](int buf) {
        ushort_t* kst = smem + buf * 8192;
        ushort_t* vst = kst + 4096;
        // K A-frags: wave's 16 rows (j = jw+lc), 2 b128
        s16x8 ak[2];
#pragma unroll
        for (int ks = 0; ks < 2; ++ks)
            ak[ks] = *(const s16x8*)(kst + (jw + lc) * 64 +
                                     (((ks * 4 + quad) ^ (lc & 7)) * 8));
        // V^T B-frags (K=16): lane needs V^T[d=df*16+lc][j=jw+quad*4+i], 4 b64
        s16x4 bv4[4];
#pragma unroll
        for (int df = 0; df < 4; ++df) {
            int row = df * 16 + lc;
            int chk = (wave * 2 + (quad >> 1)) ^ (row & 7);
            bv4[df] = *(const s16x4*)(vst + row * 64 + chk * 8 + (quad & 1) * 4);
        }
#pragma unroll
        for (int mf = 0; mf < 4; ++mf) {
            // S^T tile [16 j][16 q]: lane holds [j=quad*4+r][q=lc]
            f32x4 st = zero;
#pragma unroll
            for (int ks = 0; ks < 2; ++ks)
                st = __builtin_amdgcn_mfma_f32_16x16x32_bf16(ak[ks], qf[mf][ks], st, 0, 0, 0);
            // square -> bf16 pack; this IS the 16x16x16 A-frag for PV
            union { unsigned int u[2]; s16x4 v; } pa;
            pa.u[0] = pack2bf(st[0] * st[0], st[1] * st[1]);
            pa.u[1] = pack2bf(st[2] * st[2], st[3] * st[3]);
#pragma unroll
            for (int df = 0; df < 4; ++df)
                oacc[mf][df] = MFMA16K16(pa.v, bv4[df], oacc[mf][df]);
        }
    };

    constexpr int NT = 32;
    stage(0, 0);
    stage(1, 64);
    for (int it = 0; it < NT - 2; ++it) {
        WAIT_VM(4);
        BARRIER;
        comp(it & 1);
        WAIT_LGKM0;
        BARRIER;
        stage(it & 1, (it + 2) * 64);
    }
    WAIT_VM(4);
    BARRIER;
    comp((NT - 2) & 1);
    WAIT_VM(0);
    BARRIER;
    comp((NT - 1) & 1);

    // cross-wave j-reduction: round c reduces q-chunk c (16 rows) into wave c
    __syncthreads();
#pragma unroll
    for (int c = 0; c < 4; ++c) {
        if (wave != c) {
            int widx = wave - (wave > c ? 1 : 0);   // 0..2
#pragma unroll
            for (int df = 0; df < 4; ++df)
#pragma unroll
                for (int r = 0; r < 4; ++r)
                    red[widx * (16 * 68) + (quad * 4 + r) * 68 + df * 16 + lc] =
                        oacc[c][df][r];
        }
        __syncthreads();
        if (wave == c) {
#pragma unroll
            for (int df = 0; df < 4; ++df)
#pragma unroll
                for (int r = 0; r < 4; ++r) {
                    float v = oacc[c][df][r];
#pragma unroll
                    for (int w2 = 0; w2 < 3; ++w2)
                        v += red[w2 * (16 * 68) + (quad * 4 + r) * 68 + df * 16 + lc];
                    int s = q0 + c * 16 + quad * 4 + r;
                    int d = df * 16 + lc;
                    attn_out[((size_t)(b * SEQ + s)) * D_MODEL + h * D_K + d] = f2bf(v);
                }
        }
        __syncthreads();
    }
}

extern "C" void kernel_launch(void* const* d_in, const int* in_sizes, int n_in,
                              void* d_out, int out_size, void* d_ws, size_t ws_size,
                              hipStream_t stream)
{
    const float* Qf   = (const float*)d_in[0];
    const float* Kf   = (const float*)d_in[1];
    const float* Vf   = (const float*)d_in[2];
    const float* Wqf  = (const float*)d_in[3];
    const float* Wqbf = (const float*)d_in[4];
    const float* Wkf  = (const float*)d_in[5];
    const float* Wkbf = (const float*)d_in[6];
    const float* Wvf  = (const float*)d_in[7];
    const float* Wvbf = (const float*)d_in[8];
    const float* Wof  = (const float*)d_in[9];
    const float* Wobf = (const float*)d_in[10];

    const size_t NM = (size_t)M_TOT * D_MODEL;
    const size_t NW = (size_t)D_MODEL * D_MODEL;
    const size_t NB = D_MODEL;

    ushort_t* p = (ushort_t*)d_ws;
    ushort_t* Qb  = p;  p += NM;
    ushort_t* Kb  = p;  p += NM;
    ushort_t* Vb  = p;  p += NM;
    ushort_t* Wq  = p;  p += NW;
    ushort_t* Wk  = p;  p += NW;
    ushort_t* Wv  = p;  p += NW;
    ushort_t* Wo  = p;  p += NW;
    ushort_t* bq  = p;  p += NB;
    ushort_t* bk  = p;  p += NB;
    ushort_t* bvv = p;  p += NB;
    ushort_t* bo  = p;  p += NB;
    ushort_t* qn  = p;  p += NM;   // (B,H,S,DK)
    ushort_t* kn  = p;  p += NM;   // (B,H,S,DK)
    ushort_t* vT  = p;  p += NM;   // (B,H,DK,S)
    ushort_t* ao  = p;  p += NM;   // (B,S,D)

    ConvArgs ca;
    ca.src[0] = Qf;   ca.dst[0] = Qb;  ca.n[0] = (int)NM;
    ca.src[1] = Kf;   ca.dst[1] = Kb;  ca.n[1] = (int)NM;
    ca.src[2] = Vf;   ca.dst[2] = Vb;  ca.n[2] = (int)NM;
    ca.src[3] = Wqf;  ca.dst[3] = Wq;  ca.n[3] = (int)NW;
    ca.src[4] = Wkf;  ca.dst[4] = Wk;  ca.n[4] = (int)NW;
    ca.src[5] = Wvf;  ca.dst[5] = Wv;  ca.n[5] = (int)NW;
    ca.src[6] = Wof;  ca.dst[6] = Wo;  ca.n[6] = (int)NW;
    ca.src[7] = Wqbf; ca.dst[7] = bq;  ca.n[7] = (int)NB;
    ca.src[8] = Wkbf; ca.dst[8] = bk;  ca.n[8] = (int)NB;
    ca.src[9] = Wvbf; ca.dst[9] = bvv; ca.n[9] = (int)NB;
    ca.src[10] = Wobf; ca.dst[10] = bo; ca.n[10] = (int)NB;

    dim3 blk(256);
    convert_kernel<<<dim3((unsigned)(NM / (256 * 4)), 11), blk, 0, stream>>>(ca);

    qkv_kernel<<<dim3(M_TOT / 128, D_MODEL / 128, 3), blk, 0, stream>>>(
        Qb, Kb, Vb, Wq, Wk, Wv, bq, bk, bvv, qn, kn, vT);
    attn_kernel<<<dim3(BATCH * N_HEADS, SEQ / 64), blk, 0, stream>>>(qn, kn, vT, ao);
    wo_kernel<<<dim3(M_TOT / 64, D_MODEL / 128), blk, 0, stream>>>(
        ao, Wo, bo, (float*)d_out);
}

// Round 8
// 225.658 us; speedup vs baseline: 1.0799x; 1.0535x over previous
//
#include <hip/hip_runtime.h>
#include <hip/hip_bf16.h>

// Problem: B=2, S=2048, D_MODEL=1024, H=16, DK=64.
// out = ((l2norm(Q Wq^T) l2norm(K Wk^T)^T)^2 (V Wv^T)) Wo^T   (per head)
// fp32 in/out; internally bf16 MFMA with fp32 accumulation.
//
// Round 8 changes vs round 7 (attn only; R7: K=16 PV doubled MFMA busy
// 13.6->20.8us, inline-asm "v" constraints caused VGPR pressure / accvgpr
// shuffling -> VALUBusy 57%):
//  - back to K=32 MFMA everywhere (standard builtin only -> acc in AGPRs).
//  - QK^T j-partitioned (k-frags 2 b128/wave, no duplication; Q in regs),
//    squared P goes to a SHARED LDS P[128q][64j] with 8B-XOR swizzle
//    (conflict-free writes and reads by construction).
//  - PV q-partitioned K=32: A-frags 8 b64 from P, V^T B-frags 8 b128.
//  - 128 q/block (512 blocks, XCD pin kept), no reduction epilogue.
//  - 3 barriers/iter: tile-landed | P visible | PV done (then stage).

#define D_MODEL 1024
#define N_HEADS 16
#define D_K     64
#define BATCH   2
#define SEQ     2048
#define M_TOT   (BATCH * SEQ)   // 4096

typedef short  s16x8 __attribute__((ext_vector_type(8)));   // 8 bf16 = 4 VGPR
typedef float  f32x4 __attribute__((ext_vector_type(4)));   // MFMA C/D frag
typedef unsigned short ushort_t;
typedef ushort_t us4 __attribute__((ext_vector_type(4)));

__device__ __forceinline__ ushort_t f2bf(float f) {
    union { float f; unsigned int u; } x; x.f = f;
    unsigned int u = x.u;
    return (ushort_t)((u + 0x7fffu + ((u >> 16) & 1u)) >> 16);  // RNE
}
__device__ __forceinline__ float bf2f(ushort_t h) {
    union { unsigned int u; float f; } x; x.u = ((unsigned int)h) << 16;
    return x.f;
}
// pack two fp32 -> u32 of two bf16 (RNE)
__device__ __forceinline__ unsigned int pack2bf(float a, float b) {
    union { __hip_bfloat162 h; unsigned int u; } x;
    x.h = __float22bfloat162_rn(float2{a, b});
    return x.u;
}

// async global->LDS, 16B per lane (lane i's lds ptr == wave base + i*16).
__device__ __forceinline__ void gload_lds16(const ushort_t* g, ushort_t* l) {
    __builtin_amdgcn_global_load_lds(
        (__attribute__((address_space(1))) void*)(ushort_t*)g,
        (__attribute__((address_space(3))) void*)l, 16, 0, 0);
}

#define WAIT_VM(n)  asm volatile("s_waitcnt vmcnt(" #n ")" ::: "memory")
#define WAIT_LGKM0  asm volatile("s_waitcnt lgkmcnt(0)" ::: "memory")
#define BARRIER     asm volatile("s_barrier" ::: "memory")

// ---------------------------------------------------------------------------
// fp32 -> bf16 conversion, all 11 inputs in one launch (blockIdx.y = tensor).
// ---------------------------------------------------------------------------
struct ConvArgs {
    const float* src[11];
    ushort_t*    dst[11];
    int          n[11];
};

__global__ __launch_bounds__(256) void convert_kernel(ConvArgs a) {
    const int t = blockIdx.y;
    const int i = (blockIdx.x * 256 + threadIdx.x) * 4;
    if (i >= a.n[t]) return;
    const float4 v = *(const float4*)(a.src[t] + i);
    us4 p;
    p[0] = f2bf(v.x); p[1] = f2bf(v.y); p[2] = f2bf(v.z); p[3] = f2bf(v.w);
    *(us4*)(a.dst[t] + i) = p;
}

// ---------------------------------------------------------------------------
// GEMM body (unchanged from R7): BM x 128 tile, 4 waves 2x2, 2-deep DMA
// pipeline, BK=64. MODE 0: fp32 store  MODE 1: L2-norm -> (B,H,S,DK)
// MODE 2: transpose -> (B,H,DK,S)
// ---------------------------------------------------------------------------
template <int BM, int MODE>
__device__ __forceinline__ void gemm_body(
    ushort_t* __restrict__ smem,
    const ushort_t* __restrict__ A,
    const ushort_t* __restrict__ W,
    const ushort_t* __restrict__ bias,
    ushort_t* __restrict__ out,
    float* __restrict__ outf,
    int bx, int by)
{
    static_assert(BM == 64 || BM == 128, "");
    constexpr int K    = 1024;
    constexpr int MF   = BM / 32;
    constexpr int BUFW = (BM + 128) * 64;
    constexpr int NIT  = K / 64;

    const int t    = threadIdx.x;
    const int wave = t >> 6;
    const int lane = t & 63;
    const int quad = lane >> 4;
    const int lc   = lane & 15;
    const int wm   = wave >> 1;
    const int wn   = wave & 1;
    const int m0   = bx * BM;
    const int n0   = by * 128;

    f32x4 acc[MF][4];
    const f32x4 zero = {0.f, 0.f, 0.f, 0.f};
#pragma unroll
    for (int i = 0; i < MF; ++i)
#pragma unroll
        for (int j = 0; j < 4; ++j) acc[i][j] = zero;

    auto stage = [&](int buf, int k0) {
        ushort_t* Ast = smem + buf * BUFW;
        ushort_t* Bst = Ast + BM * 64;
#pragma unroll
        for (int c = 0; c < MF; ++c) {
            int idx = c * 256 + t;
            int row = idx >> 3, phys = idx & 7;
            int col = (phys ^ (row & 7)) * 8;
            gload_lds16(A + (size_t)(m0 + row) * K + k0 + col, Ast + idx * 8);
        }
#pragma unroll
        for (int c = 0; c < 4; ++c) {
            int idx = c * 256 + t;
            int row = idx >> 3, phys = idx & 7;
            int col = (phys ^ (row & 7)) * 8;
            gload_lds16(W + (size_t)(n0 + row) * K + k0 + col, Bst + idx * 8);
        }
    };
    auto comp = [&](int buf) {
        ushort_t* Ast = smem + buf * BUFW;
        ushort_t* Bst = Ast + BM * 64;
#pragma unroll
        for (int ks = 0; ks < 2; ++ks) {
            const int ph = ((ks * 4 + quad) ^ (lc & 7)) * 8;
            s16x8 a[MF], b[4];
#pragma unroll
            for (int i = 0; i < MF; ++i)
                a[i] = *(const s16x8*)(Ast + (wm * (BM / 2) + i * 16 + lc) * 64 + ph);
#pragma unroll
            for (int i = 0; i < 4; ++i)
                b[i] = *(const s16x8*)(Bst + (wn * 64 + i * 16 + lc) * 64 + ph);
#pragma unroll
            for (int mf = 0; mf < MF; ++mf)
#pragma unroll
                for (int nf = 0; nf < 4; ++nf)
                    acc[mf][nf] = __builtin_amdgcn_mfma_f32_16x16x32_bf16(
                        a[mf], b[nf], acc[mf][nf], 0, 0, 0);
        }
    };

    stage(0, 0);
    stage(1, 64);
    for (int it = 0; it < NIT - 2; ++it) {
        if constexpr (BM == 128) WAIT_VM(8); else WAIT_VM(6);
        BARRIER;
        comp(it & 1);
        WAIT_LGKM0;
        BARRIER;
        stage(it & 1, (it + 2) * 64);
    }
    if constexpr (BM == 128) WAIT_VM(8); else WAIT_VM(6);
    BARRIER;
    comp((NIT - 2) & 1);
    WAIT_VM(0);
    BARRIER;
    comp((NIT - 1) & 1);

    float bv[4];
#pragma unroll
    for (int nf = 0; nf < 4; ++nf) bv[nf] = bf2f(bias[n0 + wn * 64 + nf * 16 + lc]);

    if (MODE == 0) {
#pragma unroll
        for (int mf = 0; mf < MF; ++mf)
#pragma unroll
            for (int nf = 0; nf < 4; ++nf)
#pragma unroll
                for (int r = 0; r < 4; ++r) {
                    int mg = m0 + wm * (BM / 2) + mf * 16 + quad * 4 + r;
                    int ng = n0 + wn * 64 + nf * 16 + lc;
                    outf[(size_t)mg * D_MODEL + ng] = acc[mf][nf][r] + bv[nf];
                }
    } else if (MODE == 1) {
#pragma unroll
        for (int mf = 0; mf < MF; ++mf)
#pragma unroll
            for (int r = 0; r < 4; ++r) {
                float ss = 0.f;
#pragma unroll
                for (int nf = 0; nf < 4; ++nf) {
                    float v = acc[mf][nf][r] + bv[nf];
                    acc[mf][nf][r] = v;
                    ss += v * v;
                }
                ss += __shfl_xor(ss, 1);
                ss += __shfl_xor(ss, 2);
                ss += __shfl_xor(ss, 4);
                ss += __shfl_xor(ss, 8);
                float inv = rsqrtf(ss + 1e-8f);
                int mg = m0 + wm * (BM / 2) + mf * 16 + quad * 4 + r;
                int b  = mg >> 11;
                int s  = mg & 2047;
#pragma unroll
                for (int nf = 0; nf < 4; ++nf) {
                    int ng = n0 + wn * 64 + nf * 16 + lc;
                    int h = ng >> 6, d = ng & 63;
                    out[(((size_t)(b * N_HEADS + h)) * SEQ + s) * D_K + d] =
                        f2bf(acc[mf][nf][r] * inv);
                }
            }
    } else {
        __syncthreads();
        ushort_t* vt = smem + wave * (64 * 72);
#pragma unroll
        for (int mf = 0; mf < 4; ++mf)
#pragma unroll
            for (int nf = 0; nf < 4; ++nf) {
                us4 p;
#pragma unroll
                for (int r = 0; r < 4; ++r) p[r] = f2bf(acc[mf][nf][r] + bv[nf]);
                *(us4*)(vt + (nf * 16 + lc) * 72 + mf * 16 + quad * 4) = p;
            }
        WAIT_LGKM0;
#pragma unroll
        for (int r = 0; r < 8; ++r) {
            int d  = r * 8 + (lane >> 3);
            int so = (lane & 7) * 8;
            uint4 val = *(const uint4*)(vt + d * 72 + so);
            int mg = m0 + wm * 64 + so;
            int b  = mg >> 11;
            int s  = mg & 2047;
            int ng = n0 + wn * 64 + d;
            int h = ng >> 6, dh = ng & 63;
            *(uint4*)(out + (((size_t)(b * N_HEADS + h)) * D_K + dh) * SEQ + s) = val;
        }
    }
}

__global__ __launch_bounds__(256) void qkv_kernel(
    const ushort_t* __restrict__ Qb, const ushort_t* __restrict__ Kb,
    const ushort_t* __restrict__ Vb,
    const ushort_t* __restrict__ Wq, const ushort_t* __restrict__ Wk,
    const ushort_t* __restrict__ Wv,
    const ushort_t* __restrict__ bq, const ushort_t* __restrict__ bk,
    const ushort_t* __restrict__ bv,
    ushort_t* __restrict__ qn, ushort_t* __restrict__ kn,
    ushort_t* __restrict__ vT)
{
    __shared__ __align__(16) ushort_t smem[2 * (128 + 128) * 64];  // 64 KB
    const int z = blockIdx.z;
    if (z == 0)
        gemm_body<128, 1>(smem, Qb, Wq, bq, qn, nullptr, blockIdx.x, blockIdx.y);
    else if (z == 1)
        gemm_body<128, 1>(smem, Kb, Wk, bk, kn, nullptr, blockIdx.x, blockIdx.y);
    else
        gemm_body<128, 2>(smem, Vb, Wv, bv, vT, nullptr, blockIdx.x, blockIdx.y);
}

__global__ __launch_bounds__(256) void wo_kernel(
    const ushort_t* __restrict__ A, const ushort_t* __restrict__ W,
    const ushort_t* __restrict__ bias, float* __restrict__ outf)
{
    __shared__ __align__(16) ushort_t smem[2 * (64 + 128) * 64];   // 48 KB
    gemm_body<64, 0>(smem, A, W, bias, nullptr, outf, blockIdx.x, blockIdx.y);
}

// ---------------------------------------------------------------------------
// Attention: per (b,h): out = (qn kn^T)^2 v.
// Grid (x=bh 32, y=qt 16) -> 512 blocks; bh%8 pins a head to one XCD's L2.
// 128 q/block. Per 64-j k-tile:
//   QK^T: wave w owns j-slice [w*16, w*16+16): S^T = K_slice . Q^T, 16 K=32
//   MFMAs; square+pack -> shared P[128q][64j] (8B-XOR swizzle).
//   PV:   wave w owns q-slice [w*32, w*32+32): K=32 MFMAs, A from P (b64
//   swizzled reads), B = V^T rows (b128).
// ---------------------------------------------------------------------------
__global__ __launch_bounds__(256) void attn_kernel(
    const ushort_t* __restrict__ qn,
    const ushort_t* __restrict__ kn,
    const ushort_t* __restrict__ vT,
    ushort_t* __restrict__ attn_out)
{
    // staging buf i at smem+i*8192: kst [64 j][64 dk] + vst [64 d][64 j]
    __shared__ __align__(16) ushort_t smem[2 * 8192];   // 32 KB
    __shared__ __align__(16) ushort_t Pl[128 * 64];     // 16 KB, swizzled

    const int t    = threadIdx.x;
    const int wave = t >> 6;
    const int lane = t & 63;
    const int quad = lane >> 4;
    const int lc   = lane & 15;
    const int bh   = blockIdx.x;       // 0..31 (bh%8 -> XCD pin)
    const int qt   = blockIdx.y;       // 0..15
    const int b    = bh >> 4;
    const int h    = bh & 15;

    const ushort_t* qb = qn + (size_t)bh * SEQ * D_K;
    const ushort_t* kb = kn + (size_t)bh * SEQ * D_K;
    const ushort_t* vb = vT + (size_t)bh * D_K * SEQ;
    const int q0 = qt * 128;

    // Q B-frags for all 8 q-tiles of this block, reused over 32 k-tiles
    s16x8 qf[8][2];
#pragma unroll
    for (int mf = 0; mf < 8; ++mf)
#pragma unroll
        for (int ks = 0; ks < 2; ++ks)
            qf[mf][ks] = *(const s16x8*)(qb + (size_t)(q0 + mf * 16 + lc) * D_K +
                                         ks * 32 + quad * 8);

    f32x4 oacc[2][4];                  // wave's q-slice [32 q][64 d]
    const f32x4 zero = {0.f, 0.f, 0.f, 0.f};
#pragma unroll
    for (int mf = 0; mf < 2; ++mf)
#pragma unroll
        for (int df = 0; df < 4; ++df) oacc[mf][df] = zero;

    auto stage = [&](int buf, int j0) {
        ushort_t* kst = smem + buf * 8192;
        ushort_t* vst = kst + 4096;
#pragma unroll
        for (int c = 0; c < 2; ++c) {
            int idx = c * 256 + t;
            int row = idx >> 3, phys = idx & 7;
            int col = (phys ^ (row & 7)) * 8;
            gload_lds16(kb + (size_t)(j0 + row) * D_K + col, kst + idx * 8);
            gload_lds16(vb + (size_t)row * SEQ + j0 + col, vst + idx * 8);
        }
    };

    // QK^T phase: wave's 16-j slice vs all 128 q -> P
    auto qk = [&](int buf) {
        ushort_t* kst = smem + buf * 8192;
        s16x8 ak[2];
#pragma unroll
        for (int ks = 0; ks < 2; ++ks)
            ak[ks] = *(const s16x8*)(kst + (wave * 16 + lc) * 64 +
                                     (((ks * 4 + quad) ^ (lc & 7)) * 8));
        const int log8 = wave * 4 + quad;   // 8B chunk of wave's j in a P row
#pragma unroll
        for (int mf = 0; mf < 8; ++mf) {
            f32x4 st = zero;   // S^T tile: lane = [j=quad*4+r][q=lc]
#pragma unroll
            for (int ks = 0; ks < 2; ++ks)
                st = __builtin_amdgcn_mfma_f32_16x16x32_bf16(ak[ks], qf[mf][ks], st, 0, 0, 0);
            uint2 w;
            w.x = pack2bf(st[0] * st[0], st[1] * st[1]);
            w.y = pack2bf(st[2] * st[2], st[3] * st[3]);
            const int row = mf * 16 + lc;
            *(uint2*)(Pl + row * 64 + (log8 ^ lc) * 4) = w;
        }
    };

    // PV phase: wave's 32-q slice, K=32 over the 64-j tile
    auto pv = [&](int buf) {
        ushort_t* vst = smem + buf * 8192 + 4096;
        s16x8 bvf[4][2];
#pragma unroll
        for (int df = 0; df < 4; ++df)
#pragma unroll
            for (int ks = 0; ks < 2; ++ks)
                bvf[df][ks] = *(const s16x8*)(vst + (df * 16 + lc) * 64 +
                                              (((ks * 4 + quad) ^ (lc & 7)) * 8));
        s16x8 aa[2][2];
#pragma unroll
        for (int mfp = 0; mfp < 2; ++mfp)
#pragma unroll
            for (int ks = 0; ks < 2; ++ks) {
                const int row = wave * 32 + mfp * 16 + lc;
                const int l0  = ks * 8 + quad * 2;
                uint2 lo = *(const uint2*)(Pl + row * 64 + ((l0 ^ lc) * 4));
                uint2 hi = *(const uint2*)(Pl + row * 64 + (((l0 + 1) ^ lc) * 4));
                union { unsigned int u[4]; s16x8 v; } m;
                m.u[0] = lo.x; m.u[1] = lo.y; m.u[2] = hi.x; m.u[3] = hi.y;
                aa[mfp][ks] = m.v;
            }
#pragma unroll
        for (int mfp = 0; mfp < 2; ++mfp)
#pragma unroll
            for (int df = 0; df < 4; ++df)
#pragma unroll
                for (int ks = 0; ks < 2; ++ks)
                    oacc[mfp][df] = __builtin_amdgcn_mfma_f32_16x16x32_bf16(
                        aa[mfp][ks], bvf[df][ks], oacc[mfp][df], 0, 0, 0);
    };

    constexpr int NT = 32;
    stage(0, 0);
    stage(1, 64);
    for (int it = 0; it < NT; ++it) {
        if (it < NT - 1) { WAIT_VM(4); } else { WAIT_VM(0); }
        BARRIER;                       // k/v tile `it` landed everywhere
        qk(it & 1);
        WAIT_LGKM0;
        BARRIER;                       // P complete; kst reads done
        pv(it & 1);
        if (it < NT - 2) {
            WAIT_LGKM0;
            BARRIER;                   // vst + P reads done -> buf reusable
            stage(it & 1, (it + 2) * 64);
        } else if (it == NT - 2) {
            WAIT_LGKM0;
            BARRIER;                   // protect P for the last qk()
        }
    }

    // store wave's [32 q][64 d] to (B,S,D) head-interleaved bf16
#pragma unroll
    for (int mfp = 0; mfp < 2; ++mfp)
#pragma unroll
        for (int df = 0; df < 4; ++df)
#pragma unroll
            for (int r = 0; r < 4; ++r) {
                int s = q0 + wave * 32 + mfp * 16 + quad * 4 + r;
                int d = df * 16 + lc;
                attn_out[((size_t)(b * SEQ + s)) * D_MODEL + h * D_K + d] =
                    f2bf(oacc[mfp][df][r]);
            }
}

extern "C" void kernel_launch(void* const* d_in, const int* in_sizes, int n_in,
                              void* d_out, int out_size, void* d_ws, size_t ws_size,
                              hipStream_t stream)
{
    const float* Qf   = (const float*)d_in[0];
    const float* Kf   = (const float*)d_in[1];
    const float* Vf   = (const float*)d_in[2];
    const float* Wqf  = (const float*)d_in[3];
    const float* Wqbf = (const float*)d_in[4];
    const float* Wkf  = (const float*)d_in[5];
    const float* Wkbf = (const float*)d_in[6];
    const float* Wvf  = (const float*)d_in[7];
    const float* Wvbf = (const float*)d_in[8];
    const float* Wof  = (const float*)d_in[9];
    const float* Wobf = (const float*)d_in[10];

    const size_t NM = (size_t)M_TOT * D_MODEL;
    const size_t NW = (size_t)D_MODEL * D_MODEL;
    const size_t NB = D_MODEL;

    ushort_t* p = (ushort_t*)d_ws;
    ushort_t* Qb  = p;  p += NM;
    ushort_t* Kb  = p;  p += NM;
    ushort_t* Vb  = p;  p += NM;
    ushort_t* Wq  = p;  p += NW;
    ushort_t* Wk  = p;  p += NW;
    ushort_t* Wv  = p;  p += NW;
    ushort_t* Wo  = p;  p += NW;
    ushort_t* bq  = p;  p += NB;
    ushort_t* bk  = p;  p += NB;
    ushort_t* bvv = p;  p += NB;
    ushort_t* bo  = p;  p += NB;
    ushort_t* qn  = p;  p += NM;   // (B,H,S,DK)
    ushort_t* kn  = p;  p += NM;   // (B,H,S,DK)
    ushort_t* vT  = p;  p += NM;   // (B,H,DK,S)
    ushort_t* ao  = p;  p += NM;   // (B,S,D)

    ConvArgs ca;
    ca.src[0] = Qf;   ca.dst[0] = Qb;  ca.n[0] = (int)NM;
    ca.src[1] = Kf;   ca.dst[1] = Kb;  ca.n[1] = (int)NM;
    ca.src[2] = Vf;   ca.dst[2] = Vb;  ca.n[2] = (int)NM;
    ca.src[3] = Wqf;  ca.dst[3] = Wq;  ca.n[3] = (int)NW;
    ca.src[4] = Wkf;  ca.dst[4] = Wk;  ca.n[4] = (int)NW;
    ca.src[5] = Wvf;  ca.dst[5] = Wv;  ca.n[5] = (int)NW;
    ca.src[6] = Wof;  ca.dst[6] = Wo;  ca.n[6] = (int)NW;
    ca.src[7] = Wqbf; ca.dst[7] = bq;  ca.n[7] = (int)NB;
    ca.src[8] = Wkbf; ca.dst[8] = bk;  ca.n[8] = (int)NB;
    ca.src[9] = Wvbf; ca.dst[9] = bvv; ca.n[9] = (int)NB;
    ca.src[10] = Wobf; ca.dst[10] = bo; ca.n[10] = (int)NB;

    dim3 blk(256);
    convert_kernel<<<dim3((unsigned)(NM / (256 * 4)), 11), blk, 0, stream>>>(ca);

    qkv_kernel<<<dim3(M_TOT / 128, D_MODEL / 128, 3), blk, 0, stream>>>(
        Qb, Kb, Vb, Wq, Wk, Wv, bq, bk, bvv, qn, kn, vT);
    attn_kernel<<<dim3(BATCH * N_HEADS, SEQ / 128), blk, 0, stream>>>(qn, kn, vT, ao);
    wo_kernel<<<dim3(M_TOT / 64, D_MODEL / 128), blk, 0, stream>>>(
        ao, Wo, bo, (float*)d_out);
}